// Round 1
// baseline (259.196 us; speedup 1.0000x reference)
//
#include <hip/hip_runtime.h>

// MoE finalize routing: out[n,h] = sum_k scales[n,k] * (epr[esd[k*N+n], h] + bias[efr[n,k], h])
//                               + skip1[n,h] + skip2[n,h]
// drop_pad_mode == 0 (column arrangement) per setup_inputs.

#define N_ROWS 16384
#define KF 2
#define HDIM 4096
#define THREADS 256

__global__ __launch_bounds__(THREADS) void moe_finalize_kernel(
    const float* __restrict__ epr,     // [N*K, H]
    const float* __restrict__ skip1,   // [N, H]
    const float* __restrict__ skip2,   // [N, H]
    const float* __restrict__ bias,    // [E, H]
    const float* __restrict__ scales,  // [N, K]
    const int* __restrict__ esd,       // [N*K] src->dst row map
    const int* __restrict__ efr,       // [N, K] expert id per (row, k)
    float* __restrict__ out)           // [N, H]
{
    const int n = blockIdx.x;

    // Per-row scalars (wave-uniform loads; broadcast via scalar cache).
    const float s0 = scales[n * KF + 0];
    const float s1 = scales[n * KF + 1];
    const int d0 = esd[0 * N_ROWS + n];   // k = 0, column arrangement
    const int d1 = esd[1 * N_ROWS + n];   // k = 1
    const int e0 = efr[n * KF + 0];
    const int e1 = efr[n * KF + 1];

    const float4* __restrict__ r0 = (const float4*)(epr + (size_t)d0 * HDIM);
    const float4* __restrict__ r1 = (const float4*)(epr + (size_t)d1 * HDIM);
    const float4* __restrict__ b0 = (const float4*)(bias + (size_t)e0 * HDIM);
    const float4* __restrict__ b1 = (const float4*)(bias + (size_t)e1 * HDIM);
    const float4* __restrict__ k1 = (const float4*)(skip1 + (size_t)n * HDIM);
    const float4* __restrict__ k2 = (const float4*)(skip2 + (size_t)n * HDIM);
    float4* __restrict__ o = (float4*)(out + (size_t)n * HDIM);

    // H/4 = 1024 float4 per row; 256 threads -> 4 iterations, fully coalesced.
    #pragma unroll
    for (int i = threadIdx.x; i < HDIM / 4; i += THREADS) {
        const float4 a = r0[i];
        const float4 b = r1[i];
        const float4 c = b0[i];
        const float4 d = b1[i];
        const float4 x = k1[i];
        const float4 y = k2[i];
        float4 v;
        v.x = s0 * (a.x + c.x) + s1 * (b.x + d.x) + x.x + y.x;
        v.y = s0 * (a.y + c.y) + s1 * (b.y + d.y) + x.y + y.y;
        v.z = s0 * (a.z + c.z) + s1 * (b.z + d.z) + x.z + y.z;
        v.w = s0 * (a.w + c.w) + s1 * (b.w + d.w) + x.w + y.w;
        o[i] = v;
    }
}

extern "C" void kernel_launch(void* const* d_in, const int* in_sizes, int n_in,
                              void* d_out, int out_size, void* d_ws, size_t ws_size,
                              hipStream_t stream) {
    const float* epr    = (const float*)d_in[0];
    const float* skip1  = (const float*)d_in[1];
    const float* skip2  = (const float*)d_in[2];
    const float* bias   = (const float*)d_in[3];
    const float* scales = (const float*)d_in[4];
    const int*   esd    = (const int*)d_in[5];
    const int*   efr    = (const int*)d_in[6];
    float* out = (float*)d_out;

    moe_finalize_kernel<<<N_ROWS, THREADS, 0, stream>>>(
        epr, skip1, skip2, bias, scales, esd, efr, out);
}

// Round 3
// 229.559 us; speedup vs baseline: 1.1291x; 1.1291x over previous
//
#include <hip/hip_runtime.h>

// MoE finalize routing: out[n,h] = sum_k scales[n,k] * (epr[esd[k*N+n], h] + bias[efr[n,k], h])
//                               + skip1[n,h] + skip2[n,h]
// drop_pad_mode == 0 (column arrangement) per setup_inputs.

#define N_ROWS 16384
#define KF 2
#define HDIM 4096
#define THREADS 256
#define ROWS_PER_BLOCK 2

typedef float f32x4 __attribute__((ext_vector_type(4)));

__global__ __launch_bounds__(THREADS) void moe_finalize_kernel(
    const float* __restrict__ epr,     // [N*K, H]
    const float* __restrict__ skip1,   // [N, H]
    const float* __restrict__ skip2,   // [N, H]
    const float* __restrict__ bias,    // [E, H]
    const float* __restrict__ scales,  // [N, K]
    const int* __restrict__ esd,       // [N*K] src->dst row map
    const int* __restrict__ efr,       // [N, K] expert id per (row, k)
    float* __restrict__ out)           // [N, H]
{
    const int n0 = blockIdx.x * ROWS_PER_BLOCK;
    const int n1 = n0 + 1;

    // Per-row scalars (uniform, scalar-cached).
    const float s00 = scales[n0 * KF + 0], s01 = scales[n0 * KF + 1];
    const float s10 = scales[n1 * KF + 0], s11 = scales[n1 * KF + 1];
    const int d00 = esd[0 * N_ROWS + n0], d01 = esd[1 * N_ROWS + n0];
    const int d10 = esd[0 * N_ROWS + n1], d11 = esd[1 * N_ROWS + n1];
    const int e00 = efr[n0 * KF + 0], e01 = efr[n0 * KF + 1];
    const int e10 = efr[n1 * KF + 0], e11 = efr[n1 * KF + 1];

    const f32x4* __restrict__ r00 = (const f32x4*)(epr + (size_t)d00 * HDIM);
    const f32x4* __restrict__ r01 = (const f32x4*)(epr + (size_t)d01 * HDIM);
    const f32x4* __restrict__ r10 = (const f32x4*)(epr + (size_t)d10 * HDIM);
    const f32x4* __restrict__ r11 = (const f32x4*)(epr + (size_t)d11 * HDIM);
    const f32x4* __restrict__ b00 = (const f32x4*)(bias + (size_t)e00 * HDIM);
    const f32x4* __restrict__ b01 = (const f32x4*)(bias + (size_t)e01 * HDIM);
    const f32x4* __restrict__ b10 = (const f32x4*)(bias + (size_t)e10 * HDIM);
    const f32x4* __restrict__ b11 = (const f32x4*)(bias + (size_t)e11 * HDIM);
    const f32x4* __restrict__ k10 = (const f32x4*)(skip1 + (size_t)n0 * HDIM);
    const f32x4* __restrict__ k11 = (const f32x4*)(skip1 + (size_t)n1 * HDIM);
    const f32x4* __restrict__ k20 = (const f32x4*)(skip2 + (size_t)n0 * HDIM);
    const f32x4* __restrict__ k21 = (const f32x4*)(skip2 + (size_t)n1 * HDIM);
    f32x4* __restrict__ o0 = (f32x4*)(out + (size_t)n0 * HDIM);
    f32x4* __restrict__ o1 = (f32x4*)(out + (size_t)n1 * HDIM);

    // H/4 = 1024 float4 per row; 256 threads -> 4 iterations; 2 rows in flight.
    #pragma unroll
    for (int i = threadIdx.x; i < HDIM / 4; i += THREADS) {
        // Row 0 streams (non-temporal: zero reuse)
        const f32x4 a0 = __builtin_nontemporal_load(&r00[i]);
        const f32x4 b0 = __builtin_nontemporal_load(&r01[i]);
        const f32x4 x0 = __builtin_nontemporal_load(&k10[i]);
        const f32x4 y0 = __builtin_nontemporal_load(&k20[i]);
        // Row 1 streams
        const f32x4 a1 = __builtin_nontemporal_load(&r10[i]);
        const f32x4 b1 = __builtin_nontemporal_load(&r11[i]);
        const f32x4 x1 = __builtin_nontemporal_load(&k11[i]);
        const f32x4 y1 = __builtin_nontemporal_load(&k21[i]);
        // Bias (L2-resident, normal loads)
        const f32x4 c0 = b00[i];
        const f32x4 d0 = b01[i];
        const f32x4 c1 = b10[i];
        const f32x4 d1 = b11[i];

        const f32x4 v0 = s00 * (a0 + c0) + s01 * (b0 + d0) + x0 + y0;
        const f32x4 v1 = s10 * (a1 + c1) + s11 * (b1 + d1) + x1 + y1;
        __builtin_nontemporal_store(v0, &o0[i]);
        __builtin_nontemporal_store(v1, &o1[i]);
    }
}

extern "C" void kernel_launch(void* const* d_in, const int* in_sizes, int n_in,
                              void* d_out, int out_size, void* d_ws, size_t ws_size,
                              hipStream_t stream) {
    const float* epr    = (const float*)d_in[0];
    const float* skip1  = (const float*)d_in[1];
    const float* skip2  = (const float*)d_in[2];
    const float* bias   = (const float*)d_in[3];
    const float* scales = (const float*)d_in[4];
    const int*   esd    = (const int*)d_in[5];
    const int*   efr    = (const int*)d_in[6];
    float* out = (float*)d_out;

    moe_finalize_kernel<<<N_ROWS / ROWS_PER_BLOCK, THREADS, 0, stream>>>(
        epr, skip1, skip2, bias, scales, esd, efr, out);
}

// Round 4
// 228.212 us; speedup vs baseline: 1.1358x; 1.0059x over previous
//
#include <hip/hip_runtime.h>

// MoE finalize routing: out[n,h] = sum_k scales[n,k] * (epr[esd[k*N+n], h] + bias[efr[n,k], h])
//                               + skip1[n,h] + skip2[n,h]
// drop_pad_mode == 0 (column arrangement) per setup_inputs.

#define N_ROWS 16384
#define KF 2
#define HDIM 4096
#define THREADS 256
#define RPB 4   // rows per block

typedef float f32x4 __attribute__((ext_vector_type(4)));

__global__ __launch_bounds__(THREADS) void moe_finalize_kernel(
    const float* __restrict__ epr,     // [N*K, H]
    const float* __restrict__ skip1,   // [N, H]
    const float* __restrict__ skip2,   // [N, H]
    const float* __restrict__ bias,    // [E, H]
    const float* __restrict__ scales,  // [N, K]
    const int* __restrict__ esd,       // [N*K] src->dst row map
    const int* __restrict__ efr,       // [N, K] expert id per (row, k)
    float* __restrict__ out)           // [N, H]
{
    const int nbase = blockIdx.x * RPB;

    float s0[RPB], s1[RPB];
    const f32x4* r0[RPB];
    const f32x4* r1[RPB];
    const f32x4* b0[RPB];
    const f32x4* b1[RPB];
    const f32x4* p1[RPB];
    const f32x4* p2[RPB];
    f32x4* o[RPB];

    #pragma unroll
    for (int r = 0; r < RPB; ++r) {
        const int n = nbase + r;
        s0[r] = scales[n * KF + 0];
        s1[r] = scales[n * KF + 1];
        const int d0 = esd[0 * N_ROWS + n];   // k = 0, column arrangement
        const int d1 = esd[1 * N_ROWS + n];   // k = 1
        const int e0 = efr[n * KF + 0];
        const int e1 = efr[n * KF + 1];
        r0[r] = (const f32x4*)(epr + (size_t)d0 * HDIM);
        r1[r] = (const f32x4*)(epr + (size_t)d1 * HDIM);
        b0[r] = (const f32x4*)(bias + (size_t)e0 * HDIM);
        b1[r] = (const f32x4*)(bias + (size_t)e1 * HDIM);
        p1[r] = (const f32x4*)(skip1 + (size_t)n * HDIM);
        p2[r] = (const f32x4*)(skip2 + (size_t)n * HDIM);
        o[r]  = (f32x4*)(out + (size_t)n * HDIM);
    }

    // H/4 = 1024 float4 per row; 256 threads -> 4 i-iterations; RPB rows in flight.
    #pragma unroll
    for (int i = threadIdx.x; i < HDIM / 4; i += THREADS) {
        f32x4 a[RPB], b[RPB], x[RPB], y[RPB], c[RPB], d[RPB];
        // Issue all streaming loads first (nt: zero reuse), then bias (L2-hot).
        #pragma unroll
        for (int r = 0; r < RPB; ++r) {
            a[r] = __builtin_nontemporal_load(&r0[r][i]);
            b[r] = __builtin_nontemporal_load(&r1[r][i]);
            x[r] = __builtin_nontemporal_load(&p1[r][i]);
            y[r] = __builtin_nontemporal_load(&p2[r][i]);
        }
        #pragma unroll
        for (int r = 0; r < RPB; ++r) {
            c[r] = b0[r][i];
            d[r] = b1[r][i];
        }
        #pragma unroll
        for (int r = 0; r < RPB; ++r) {
            const f32x4 v = s0[r] * (a[r] + c[r]) + s1[r] * (b[r] + d[r]) + x[r] + y[r];
            __builtin_nontemporal_store(v, &o[r][i]);
        }
    }
}

extern "C" void kernel_launch(void* const* d_in, const int* in_sizes, int n_in,
                              void* d_out, int out_size, void* d_ws, size_t ws_size,
                              hipStream_t stream) {
    const float* epr    = (const float*)d_in[0];
    const float* skip1  = (const float*)d_in[1];
    const float* skip2  = (const float*)d_in[2];
    const float* bias   = (const float*)d_in[3];
    const float* scales = (const float*)d_in[4];
    const int*   esd    = (const int*)d_in[5];
    const int*   efr    = (const int*)d_in[6];
    float* out = (float*)d_out;

    moe_finalize_kernel<<<N_ROWS / RPB, THREADS, 0, stream>>>(
        epr, skip1, skip2, bias, scales, esd, efr, out);
}